// Round 1
// baseline (1263.264 us; speedup 1.0000x reference)
//
#include <hip/hip_runtime.h>
#include <cstdint>

#define NB   8
#define NC   64
#define NPTS 4096
#define NK   16
#define CAP  16
#define SPLIT 4
#define CHUNK (NPTS / SPLIT)

// ---------------------------------------------------------------------------
// insert r,m into sorted-descending top-16 (D[0] = worst). Caller guarantees
// r < D[0]. Branchless shift: D_new[i] = c[i+1]?D[i+1]:(c[i]?r:D[i]).
// ---------------------------------------------------------------------------
__device__ __forceinline__ void insert16(float (&D)[16], int (&M)[16], float r, int m) {
  bool c[16];
#pragma unroll
  for (int i = 0; i < 16; ++i) c[i] = (D[i] > r);
#pragma unroll
  for (int i = 0; i < 16; ++i) {
    bool  cn = (i < 15) ? c[i + 1] : false;
    float dn = (i < 15) ? D[i + 1] : 0.f;
    int   mn = (i < 15) ? M[i + 1] : 0;
    float dv = cn ? dn : (c[i] ? r : D[i]);
    int   mv = cn ? mn : (c[i] ? m : M[i]);
    D[i] = dv;
    M[i] = mv;
  }
}

// ---------------------------------------------------------------------------
// A: transpose x [B,C,N] -> XT [B,N,C] (row per point, 256B rows) + sq[b,n]
// ---------------------------------------------------------------------------
__global__ __launch_bounds__(256) void k_transpose(const float* __restrict__ x,
                                                   float* __restrict__ xt,
                                                   float* __restrict__ sq) {
  __shared__ float tile[64][65];
  const int b  = blockIdx.y;
  const int n0 = blockIdx.x * 64;
  const int t  = threadIdx.x;
#pragma unroll
  for (int i = 0; i < 16; ++i) {
    int lin = i * 256 + t;
    int c = lin >> 6, j = lin & 63;
    tile[j][c] = x[(size_t)b * NC * NPTS + (size_t)c * NPTS + n0 + j];
  }
  __syncthreads();
#pragma unroll
  for (int i = 0; i < 16; ++i) {
    int lin = i * 256 + t;
    int j = lin >> 6, c = lin & 63;
    xt[((size_t)b * NPTS + n0 + j) * NC + c] = tile[j][c];
  }
  if (t < 64) {
    float s = 0.f;
#pragma unroll
    for (int c = 0; c < 64; ++c) { float v = tile[t][c]; s = fmaf(v, v, s); }
    sq[b * NPTS + n0 + t] = s;
  }
}

// ---------------------------------------------------------------------------
// B: P[n][o] = W1[o]·xt[n] ;  Q[n][o] = (W2-W1)[o]·xt[n] + b1[o] + b2[o]
// W accessed with uniform indices -> scalar loads (K$), FMAs vgpr*sgpr.
// ---------------------------------------------------------------------------
__global__ __launch_bounds__(256) void k_pq(const float* __restrict__ xt,
                                            const float* __restrict__ W1,
                                            const float* __restrict__ b1,
                                            const float* __restrict__ W2,
                                            const float* __restrict__ b2,
                                            float* __restrict__ P,
                                            float* __restrict__ Q) {
  const int gn = blockIdx.x * 256 + threadIdx.x;  // 0 .. B*N-1
  float cen[64];
#pragma unroll
  for (int c = 0; c < 64; ++c) cen[c] = xt[(size_t)gn * 64 + c];
  for (int o = 0; o < 64; ++o) {
    float p = 0.f, q2 = 0.f;
#pragma unroll
    for (int c = 0; c < 64; ++c) {
      p  = fmaf(W1[o * 64 + c], cen[c], p);
      q2 = fmaf(W2[o * 64 + c], cen[c], q2);
    }
    P[(size_t)gn * 64 + o] = p;
    Q[(size_t)gn * 64 + o] = q2 - p + b1[o] + b2[o];
  }
}

// ---------------------------------------------------------------------------
// C: partial KNN. Thread-per-row, chunk of 1024 candidate columns.
// Neighbor row address is block-uniform -> s_load; center in VGPRs.
// Candidates passing stale threshold buffered in LDS; wave-voted batch flush.
// ---------------------------------------------------------------------------
__global__ __launch_bounds__(256) void k_knn_partial(const float* __restrict__ xt,
                                                     const float* __restrict__ sq,
                                                     float* __restrict__ part_d,
                                                     int* __restrict__ part_m) {
  __shared__ float bufr[256 * 17];
  __shared__ int   bufm[256 * 17];
  const int tid = threadIdx.x;
  const int bx  = blockIdx.x;            // 0..127
  const int b   = bx >> 4;               // uniform (divergence-analysis friendly)
  const int n   = ((bx & 15) << 8) + tid; // row within batch
  const int gn  = (b << 12) + n;
  const int m0  = blockIdx.y * CHUNK;

  float cen[64];
#pragma unroll
  for (int c = 0; c < 64; ++c) cen[c] = xt[(size_t)gn * 64 + c];

  float D[16]; int M[16];
#pragma unroll
  for (int i = 0; i < 16; ++i) { D[i] = 1e30f; M[i] = 0; }
  int cnt = 0;

  const float* xb  = xt + (size_t)b * NPTS * 64;   // uniform
  const float* sqb = sq + (size_t)b * NPTS;        // uniform

  for (int m = m0; m < m0 + CHUNK; ++m) {
    const float* xm = xb + (size_t)m * 64;         // uniform -> s_load
    float d0 = 0.f, d1 = 0.f, d2 = 0.f, d3 = 0.f;
#pragma unroll
    for (int c = 0; c < 64; c += 4) {
      d0 = fmaf(cen[c + 0], xm[c + 0], d0);
      d1 = fmaf(cen[c + 1], xm[c + 1], d1);
      d2 = fmaf(cen[c + 2], xm[c + 2], d2);
      d3 = fmaf(cen[c + 3], xm[c + 3], d3);
    }
    float r = sqb[m] - 2.f * ((d0 + d1) + (d2 + d3));  // rank key: dist - sq[n]
    bool pass = (r < D[0]) && (m != n);
    if (pass) {
      bufr[tid * 17 + cnt] = r;
      bufm[tid * 17 + cnt] = m;
      cnt++;
    }
    if (__any(cnt == CAP)) {
#pragma unroll 1
      for (int i = 0; i < CAP; ++i) {
        if (i < cnt) {
          float rr = bufr[tid * 17 + i];
          int   mm = bufm[tid * 17 + i];
          if (rr < D[0]) insert16(D, M, rr, mm);
        }
      }
      cnt = 0;
    }
  }
#pragma unroll 1
  for (int i = 0; i < CAP; ++i) {
    if (i < cnt) {
      float rr = bufr[tid * 17 + i];
      int   mm = bufm[tid * 17 + i];
      if (rr < D[0]) insert16(D, M, rr, mm);
    }
  }
  const size_t base = ((size_t)gn * SPLIT + blockIdx.y) * 16;
#pragma unroll
  for (int i = 0; i < 16; ++i) {
    part_d[base + i] = D[i];
    part_m[base + i] = M[i];
  }
}

// ---------------------------------------------------------------------------
// C2: merge SPLIT partial top-16 lists -> final 16 neighbor indices per row
// ---------------------------------------------------------------------------
__global__ __launch_bounds__(256) void k_merge(const float* __restrict__ part_d,
                                               const int* __restrict__ part_m,
                                               int* __restrict__ knn) {
  const int gn = blockIdx.x * 256 + threadIdx.x;
  float D[16]; int M[16];
#pragma unroll
  for (int i = 0; i < 16; ++i) { D[i] = 1e30f; M[i] = 0; }
#pragma unroll 1
  for (int s = 0; s < SPLIT; ++s) {
#pragma unroll 1
    for (int i = 0; i < 16; ++i) {
      float r = part_d[((size_t)gn * SPLIT + s) * 16 + i];
      int   m = part_m[((size_t)gn * SPLIT + s) * 16 + i];
      if (r < D[0]) insert16(D, M, r, m);
    }
  }
#pragma unroll
  for (int i = 0; i < 16; ++i) knn[(size_t)gn * 16 + i] = M[i];
}

// ---------------------------------------------------------------------------
// D: y[n][o] = relu(max_k (Q[n][o] + P[knn[n][k]][o]))  (relu commutes w/ max)
// wave per point (lane = o), LDS transpose for coalesced [B,Cout,1,N] writes
// ---------------------------------------------------------------------------
__global__ __launch_bounds__(256) void k_out(const float* __restrict__ P,
                                             const float* __restrict__ Q,
                                             const int* __restrict__ knn,
                                             float* __restrict__ out) {
  __shared__ float tile[64][65];
  const int b    = blockIdx.y;
  const int n0   = blockIdx.x * 64;
  const int wave = threadIdx.x >> 6;
  const int lane = threadIdx.x & 63;
  for (int i = 0; i < 16; ++i) {
    const int nl = wave * 16 + i;
    const int gn = b * NPTS + n0 + nl;
    float acc = -1e30f;
    const float q = Q[(size_t)gn * 64 + lane];
    const int* id = knn + (size_t)gn * 16;
#pragma unroll
    for (int k = 0; k < 16; ++k) {
      int m = id[k];
      float p = P[((size_t)b * NPTS + m) * 64 + lane];
      acc = fmaxf(acc, q + p);
    }
    tile[nl][lane] = fmaxf(acc, 0.f);
  }
  __syncthreads();
#pragma unroll
  for (int i = 0; i < 16; ++i) {
    const int o = i * 4 + wave;
    out[((size_t)b * 64 + o) * NPTS + n0 + lane] = tile[lane][o];
  }
}

// ---------------------------------------------------------------------------
extern "C" void kernel_launch(void* const* d_in, const int* in_sizes, int n_in,
                              void* d_out, int out_size, void* d_ws, size_t ws_size,
                              hipStream_t stream) {
  const float* x  = (const float*)d_in[0];
  const float* W1 = (const float*)d_in[1];
  const float* b1 = (const float*)d_in[2];
  const float* W2 = (const float*)d_in[3];
  const float* b2 = (const float*)d_in[4];
  float* out = (float*)d_out;

  // workspace carve-up (element offsets)
  float* ws = (float*)d_ws;
  const size_t NPT_ALL = (size_t)NB * NPTS;          // 32768
  float* XT     = ws;                                 // 2,097,152 f
  float* SQ     = XT + NPT_ALL * 64;                  //    32,768 f
  float* Pm     = SQ + NPT_ALL;                       // 2,097,152 f
  float* Qm     = Pm + NPT_ALL * 64;                  // 2,097,152 f
  float* PARTD  = Qm + NPT_ALL * 64;                  // 2,097,152 f
  int*   PARTM  = (int*)(PARTD + NPT_ALL * SPLIT * 16);
  int*   KNNIDX = PARTM + NPT_ALL * SPLIT * 16;       //   524,288 i

  k_transpose<<<dim3(NPTS / 64, NB), 256, 0, stream>>>(x, XT, SQ);
  k_pq<<<dim3(NPT_ALL / 256), 256, 0, stream>>>(XT, W1, b1, W2, b2, Pm, Qm);
  k_knn_partial<<<dim3(NPT_ALL / 256, SPLIT), 256, 0, stream>>>(XT, SQ, PARTD, PARTM);
  k_merge<<<dim3(NPT_ALL / 256), 256, 0, stream>>>(PARTD, PARTM, KNNIDX);
  k_out<<<dim3(NPTS / 64, NB), 256, 0, stream>>>(Pm, Qm, KNNIDX, out);
}

// Round 2
// 638.969 us; speedup vs baseline: 1.9770x; 1.9770x over previous
//
#include <hip/hip_runtime.h>
#include <cstdint>

#define NB    8
#define NC    64
#define NPTS  4096
#define NK    16
#define SPLIT 8
#define CHUNK (NPTS / SPLIT)   // 512
#define SLOTS 13               // LDS defer-buffer slots per thread (stride 13: coprime w/ 32 banks)
#define FLUSH_AT 10            // vote threshold; <= 2 appends between votes -> never exceeds SLOTS

// ---------------------------------------------------------------------------
// insert r,m into sorted-descending top-16 (D[0] = worst). Caller guarantees
// r < D[0]. Branchless shift.
// ---------------------------------------------------------------------------
__device__ __forceinline__ void insert16(float (&D)[16], int (&M)[16], float r, int m) {
  bool c[16];
#pragma unroll
  for (int i = 0; i < 16; ++i) c[i] = (D[i] > r);
#pragma unroll
  for (int i = 0; i < 16; ++i) {
    bool  cn = (i < 15) ? c[i + 1] : false;
    float dn = (i < 15) ? D[i + 1] : 0.f;
    int   mn = (i < 15) ? M[i + 1] : 0;
    float dv = cn ? dn : (c[i] ? r : D[i]);
    int   mv = cn ? mn : (c[i] ? m : M[i]);
    D[i] = dv;
    M[i] = mv;
  }
}

// ---------------------------------------------------------------------------
// A: transpose x [B,C,N] -> XT [B,N,C] (row per point, 256B rows) + sq[b,n]
// ---------------------------------------------------------------------------
__global__ __launch_bounds__(256) void k_transpose(const float* __restrict__ x,
                                                   float* __restrict__ xt,
                                                   float* __restrict__ sq) {
  __shared__ float tile[64][65];
  const int b  = blockIdx.y;
  const int n0 = blockIdx.x * 64;
  const int t  = threadIdx.x;
#pragma unroll
  for (int i = 0; i < 16; ++i) {
    int lin = i * 256 + t;
    int c = lin >> 6, j = lin & 63;
    tile[j][c] = x[(size_t)b * NC * NPTS + (size_t)c * NPTS + n0 + j];
  }
  __syncthreads();
#pragma unroll
  for (int i = 0; i < 16; ++i) {
    int lin = i * 256 + t;
    int j = lin >> 6, c = lin & 63;
    xt[((size_t)b * NPTS + n0 + j) * NC + c] = tile[j][c];
  }
  if (t < 64) {
    float s = 0.f;
#pragma unroll
    for (int c = 0; c < 64; ++c) { float v = tile[t][c]; s = fmaf(v, v, s); }
    sq[b * NPTS + n0 + t] = s;
  }
}

// ---------------------------------------------------------------------------
// B: P[n][o] = W1[o]·xt[n] ;  Q[n][o] = (W2-W1)[o]·xt[n] + b1[o] + b2[o]
// o-tiled grid (y in 0..3 -> 16 outputs each) so grid = 512 blocks (2/CU).
// ---------------------------------------------------------------------------
__global__ __launch_bounds__(256, 4) void k_pq(const float* __restrict__ xt,
                                               const float* __restrict__ W1,
                                               const float* __restrict__ b1,
                                               const float* __restrict__ W2,
                                               const float* __restrict__ b2,
                                               float* __restrict__ P,
                                               float* __restrict__ Q) {
  const int gn = blockIdx.x * 256 + threadIdx.x;  // 0 .. B*N-1
  const int o0 = blockIdx.y * 16;
  float cen[64];
#pragma unroll
  for (int c = 0; c < 64; ++c) cen[c] = xt[(size_t)gn * 64 + c];
#pragma unroll 1
  for (int oi = 0; oi < 16; ++oi) {
    const int o = o0 + oi;
    float p = 0.f, q2 = 0.f;
#pragma unroll
    for (int c = 0; c < 64; ++c) {
      p  = fmaf(W1[o * 64 + c], cen[c], p);
      q2 = fmaf(W2[o * 64 + c], cen[c], q2);
    }
    P[(size_t)gn * 64 + o] = p;
    Q[(size_t)gn * 64 + o] = q2 - p + b1[o] + b2[o];
  }
}

// ---------------------------------------------------------------------------
// C: partial KNN. Thread-per-row; 512-candidate chunk; m-loop unrolled x2
// (4 independent FMA chains, 2 scalar row-loads in flight). Candidates
// passing the stale threshold defer to LDS; wave-voted batch flush.
// ---------------------------------------------------------------------------
__global__ __launch_bounds__(256, 4) void k_knn_partial(const float* __restrict__ xt,
                                                        const float* __restrict__ sq,
                                                        float* __restrict__ part_d,
                                                        short* __restrict__ part_m) {
  __shared__ float bufr[256 * SLOTS];
  __shared__ int   bufm[256 * SLOTS];
  const int tid = threadIdx.x;
  const int bx  = blockIdx.x;             // 0..127
  const int b   = bx >> 4;                // uniform
  const int n   = ((bx & 15) << 8) + tid; // row within batch
  const int gn  = (b << 12) + n;
  const int m0  = blockIdx.y * CHUNK;

  float cen[64];
#pragma unroll
  for (int c = 0; c < 64; ++c) cen[c] = xt[(size_t)gn * 64 + c];

  float D[16]; int M[16];
#pragma unroll
  for (int i = 0; i < 16; ++i) { D[i] = 1e30f; M[i] = 0; }
  int cnt = 0;

  const float* xb  = xt + (size_t)b * NPTS * 64;   // uniform
  const float* sqb = sq + (size_t)b * NPTS;        // uniform

  for (int m = m0; m < m0 + CHUNK; m += 2) {
    const float* xa = xb + (size_t)m * 64;         // uniform -> s_load
    const float* xc = xa + 64;
    float a0 = 0.f, a1 = 0.f, c0 = 0.f, c1 = 0.f;
#pragma unroll
    for (int c = 0; c < 64; c += 2) {
      a0 = fmaf(cen[c + 0], xa[c + 0], a0);
      a1 = fmaf(cen[c + 1], xa[c + 1], a1);
      c0 = fmaf(cen[c + 0], xc[c + 0], c0);
      c1 = fmaf(cen[c + 1], xc[c + 1], c1);
    }
    float r0 = sqb[m]     - 2.f * (a0 + a1);   // rank key: dist - sq[n]
    float r1 = sqb[m + 1] - 2.f * (c0 + c1);
    bool p0 = (r0 < D[0]) & (m != n);
    bool p1 = (r1 < D[0]) & ((m + 1) != n);
    if (p0) { bufr[tid * SLOTS + cnt] = r0; bufm[tid * SLOTS + cnt] = m;     cnt++; }
    if (p1) { bufr[tid * SLOTS + cnt] = r1; bufm[tid * SLOTS + cnt] = m + 1; cnt++; }
    if (__any(cnt >= FLUSH_AT)) {
#pragma unroll 1
      for (int i = 0; i < SLOTS; ++i) {
        if (__ballot(i < cnt) == 0ull) break;
        if (i < cnt) {
          float rr = bufr[tid * SLOTS + i];
          int   mm = bufm[tid * SLOTS + i];
          if (rr < D[0]) insert16(D, M, rr, mm);
        }
      }
      cnt = 0;
    }
  }
#pragma unroll 1
  for (int i = 0; i < SLOTS; ++i) {
    if (__ballot(i < cnt) == 0ull) break;
    if (i < cnt) {
      float rr = bufr[tid * SLOTS + i];
      int   mm = bufm[tid * SLOTS + i];
      if (rr < D[0]) insert16(D, M, rr, mm);
    }
  }
  const size_t base = ((size_t)gn * SPLIT + blockIdx.y) * 16;
#pragma unroll
  for (int i = 0; i < 16; ++i) {
    part_d[base + i] = D[i];
    part_m[base + i] = (short)M[i];
  }
}

// ---------------------------------------------------------------------------
// C2: merge SPLIT partial top-16 lists -> final 16 neighbor indices per row
// ---------------------------------------------------------------------------
__global__ __launch_bounds__(128) void k_merge(const float* __restrict__ part_d,
                                               const short* __restrict__ part_m,
                                               int* __restrict__ knn) {
  const int gn = blockIdx.x * 128 + threadIdx.x;
  float D[16]; int M[16];
#pragma unroll
  for (int i = 0; i < 16; ++i) { D[i] = 1e30f; M[i] = 0; }
#pragma unroll 1
  for (int s = 0; s < SPLIT; ++s) {
#pragma unroll 1
    for (int i = 0; i < 16; ++i) {
      float r = part_d[((size_t)gn * SPLIT + s) * 16 + i];
      int   m = part_m[((size_t)gn * SPLIT + s) * 16 + i];
      if (r < D[0]) insert16(D, M, r, m);
    }
  }
#pragma unroll
  for (int i = 0; i < 16; ++i) knn[(size_t)gn * 16 + i] = M[i];
}

// ---------------------------------------------------------------------------
// D: y[n][o] = relu(max_k (Q[n][o] + P[knn[n][k]][o]))  (relu commutes w/ max)
// wave per point (lane = o), LDS transpose for coalesced [B,Cout,1,N] writes
// ---------------------------------------------------------------------------
__global__ __launch_bounds__(256) void k_out(const float* __restrict__ P,
                                             const float* __restrict__ Q,
                                             const int* __restrict__ knn,
                                             float* __restrict__ out) {
  __shared__ float tile[64][65];
  const int b    = blockIdx.y;
  const int n0   = blockIdx.x * 64;
  const int wave = threadIdx.x >> 6;
  const int lane = threadIdx.x & 63;
  for (int i = 0; i < 16; ++i) {
    const int nl = wave * 16 + i;
    const int gn = b * NPTS + n0 + nl;
    float acc = -1e30f;
    const float q = Q[(size_t)gn * 64 + lane];
    const int* id = knn + (size_t)gn * 16;
#pragma unroll
    for (int k = 0; k < 16; ++k) {
      int m = id[k];
      float p = P[((size_t)b * NPTS + m) * 64 + lane];
      acc = fmaxf(acc, q + p);
    }
    tile[nl][lane] = fmaxf(acc, 0.f);
  }
  __syncthreads();
#pragma unroll
  for (int i = 0; i < 16; ++i) {
    const int o = i * 4 + wave;
    out[((size_t)b * 64 + o) * NPTS + n0 + lane] = tile[lane][o];
  }
}

// ---------------------------------------------------------------------------
extern "C" void kernel_launch(void* const* d_in, const int* in_sizes, int n_in,
                              void* d_out, int out_size, void* d_ws, size_t ws_size,
                              hipStream_t stream) {
  const float* x  = (const float*)d_in[0];
  const float* W1 = (const float*)d_in[1];
  const float* b1 = (const float*)d_in[2];
  const float* W2 = (const float*)d_in[3];
  const float* b2 = (const float*)d_in[4];
  float* out = (float*)d_out;

  // workspace carve-up (element offsets). P/Q reuse the partials region
  // (pq launches AFTER merge; stream-ordered so partials are dead by then).
  float* ws = (float*)d_ws;
  const size_t NPT_ALL = (size_t)NB * NPTS;              // 32768
  float* XT     = ws;                                     // 2,097,152 f
  float* SQ     = XT + NPT_ALL * 64;                      //    32,768 f
  float* PARTD  = SQ + NPT_ALL;                           // 4,194,304 f
  short* PARTM  = (short*)(PARTD + NPT_ALL * SPLIT * 16); // 4,194,304 s (2,097,152 f)
  int*   KNNIDX = (int*)(PARTM + NPT_ALL * SPLIT * 16);   //   524,288 i
  float* Pm     = PARTD;                                  // reuse (post-merge)
  float* Qm     = Pm + NPT_ALL * 64;

  k_transpose<<<dim3(NPTS / 64, NB), 256, 0, stream>>>(x, XT, SQ);
  k_knn_partial<<<dim3(NPT_ALL / 256, SPLIT), 256, 0, stream>>>(XT, SQ, PARTD, PARTM);
  k_merge<<<dim3(NPT_ALL / 128), 128, 0, stream>>>(PARTD, PARTM, KNNIDX);
  k_pq<<<dim3(NPT_ALL / 256, 4), 256, 0, stream>>>(XT, W1, b1, W2, b2, Pm, Qm);
  k_out<<<dim3(NPTS / 64, NB), 256, 0, stream>>>(Pm, Qm, KNNIDX, out);
}